// Round 7
// baseline (255.765 us; speedup 1.0000x reference)
//
#include <hip/hip_runtime.h>
#include <cstdint>
#include <cstddef>

// Problem constants (fixed by reference).
#define BATCH 16
#define SEQ   4096
#define NS    512
#define TLAG  128            // truncation: ||A^128|| ~ 1e-5 -> error ~1e-4 << bf16 noise
#define CTILE 256            // conv time-tile rows per block (round 7: was 128)
#define XROWS (CTILE + TLAG - 1)   // 383 staged rows
#define XSTR  72             // LDS row stride in u16 (144 B = 9*16B, 16B-aligned)
#define BLK   32768          // one 64x512 row-block in u16 (64*512)

typedef unsigned short u16;
typedef unsigned int   u32;
typedef short bf16x8 __attribute__((ext_vector_type(8)));   // 8 bf16 = 4 VGPRs
typedef float f32x4  __attribute__((ext_vector_type(4)));   // MFMA accumulator

__device__ __forceinline__ u16 f2bf(float f) {
    u32 u = __builtin_bit_cast(u32, f);
    return (u16)((u + 0x7FFFu + ((u >> 16) & 1u)) >> 16);   // RNE
}
__device__ __forceinline__ float bf2f(u16 h) {
    return __builtin_bit_cast(float, (u32)h << 16);
}

// ---------------------------------------------------------------------------
// prep_mat: matrix-only input conversion (x conversion moved INTO conv).
//  A -> Arm + At; B -> Rt[0] (= B^T); C -> L[0]. 1280 blocks x 256 = 327,680.
// ---------------------------------------------------------------------------
__global__ __launch_bounds__(256) void prep_mat(const float* __restrict__ A,
                                                const float* __restrict__ B,
                                                const float* __restrict__ C,
                                                u16* __restrict__ Arm,
                                                u16* __restrict__ At,
                                                u16* __restrict__ Rt,
                                                u16* __restrict__ L)
{
    const int id = blockIdx.x * 256 + threadIdx.x;
    if (id < 262144) {                                 // A: 512x512
        const int c = id & 511;
        const u16 v = f2bf(A[id]);
        Arm[id] = v;
        At[(size_t)c * 512 + (id >> 9)] = v;
    } else if (id < 262144 + 32768) {                  // B: 512x64 -> B^T (=R_0^T)
        const int i = id - 262144;
        Rt[(size_t)(i & 63) * 512 + (i >> 6)] = f2bf(B[i]);
    } else {                                           // C: 64x512 -> L_0
        const int i = id - 262144 - 32768;             // < 65536
        L[i] = f2bf(C[i]);
    }
}

// ---------------------------------------------------------------------------
// gemm_tile: one 64(M)x64(N) output tile, K=512, bf16 in / fp32 acc / bf16
// out. Aop row-major [64][512]; bT [N_total][512] (operand-B transposed), n0
// selects the 64-col slice. oRM row-major out via LDS bounce; oT transposed
// out (absolute row rowT). Plain cached stores -- kernel boundaries provide
// coherence (rounds 0/4 proven). block = 256 (4 waves x 16 rows).
// ---------------------------------------------------------------------------
__device__ __forceinline__ void gemm_tile(const u16* __restrict__ apM,
                                          const u16* __restrict__ bT, int n0,
                                          u16* __restrict__ oRM,
                                          u16* __restrict__ oT, int rowT,
                                          u16* __restrict__ lds)
{
    const int tid = threadIdx.x;
    const int w = tid >> 6, l = tid & 63;
    const int lr = l & 15, q8 = (l >> 4) * 8;

    const u16* ap  = apM + (size_t)(w * 16 + lr) * NS + q8;
    const u16* bp0 = bT  + (size_t)(n0 + lr) * NS + q8;

    f32x4 acc[4];
    const f32x4 zero = {0.f, 0.f, 0.f, 0.f};
    #pragma unroll
    for (int nt = 0; nt < 4; ++nt) acc[nt] = zero;

    #pragma unroll 4
    for (int ks = 0; ks < 16; ++ks) {
        const bf16x8 a = *(const bf16x8*)(ap + ks * 32);
        #pragma unroll
        for (int nt = 0; nt < 4; ++nt) {
            const bf16x8 bfr = *(const bf16x8*)(bp0 + (size_t)nt * 16 * NS + ks * 32);
            acc[nt] = __builtin_amdgcn_mfma_f32_16x16x32_bf16(a, bfr, acc[nt], 0, 0, 0);
        }
    }

    const int rr = (l >> 4) * 4;    // C/D: row = (lane>>4)*4 + reg, col = lane&15
    if (oT) {
        #pragma unroll
        for (int nt = 0; nt < 4; ++nt) {
            const int col = n0 + nt * 16 + lr;
            ushort4 pk;
            pk.x = f2bf(acc[nt][0]); pk.y = f2bf(acc[nt][1]);
            pk.z = f2bf(acc[nt][2]); pk.w = f2bf(acc[nt][3]);
            *(ushort4*)(oT + (size_t)col * NS + rowT + w * 16 + rr) = pk;
        }
    }
    if (oRM) {
        #pragma unroll
        for (int nt = 0; nt < 4; ++nt)
            #pragma unroll
            for (int r = 0; r < 4; ++r)
                lds[(w * 16 + rr + r) * 72 + nt * 16 + lr] = f2bf(acc[nt][r]);
        __syncthreads();
        const int r  = tid >> 2;             // 0..63
        const int c0 = (tid & 3) * 16;       // 0,16,32,48
        #pragma unroll
        for (int k = 0; k < 4; ++k) {
            const ushort4 q = *(const ushort4*)&lds[r * 72 + c0 + k * 4];
            *(ushort4*)(oRM + (size_t)r * NS + n0 + c0 + k * 4) = q;
        }
    }
}

// ---------------------------------------------------------------------------
// stage_kernel: one doubling stage (round-4 verified). grid = E + (sq?64:0).
//  blocks [0,E):    expansion tiles: out[j] = Aop[j] x BTop-slice
//  blocks [E,E+64): squaring tiles: A^{2h} = A^h * A^h, RM (+T if sqOutT).
// ---------------------------------------------------------------------------
__global__ __launch_bounds__(256, 1) void stage_kernel(const u16* __restrict__ expAp,
                                                       const u16* __restrict__ expBT,
                                                       u16* __restrict__ expOut,
                                                       const u16* __restrict__ sqIn,
                                                       const u16* __restrict__ sqInT,
                                                       u16* __restrict__ sqOutRM,
                                                       u16* __restrict__ sqOutT,
                                                       int E)
{
    __shared__ u16 lds[64 * 72];   // 9,216 B bounce buffer
    const int t = blockIdx.x;
    if (t < E) {
        const int j = t >> 3, n0 = (t & 7) * 64;
        gemm_tile(expAp + (size_t)j * BLK, expBT, n0,
                  expOut + (size_t)j * BLK, nullptr, 0, lds);
    } else {
        const int tt = t - E;
        const int mr = tt >> 3, n0 = (tt & 7) * 64;
        gemm_tile(sqIn + (size_t)mr * BLK, sqInT, n0,
                  sqOutRM + (size_t)mr * BLK, sqOutT, mr * 64, lds);
    }
}

// ---------------------------------------------------------------------------
// g_kernel: G_m (m = blockIdx.x) via G^T = R_q^T x L_r (q=m>>4, r=m&15).
// Epilogue: bounce to lds[o][i], B-fragment swizzle read + D fold (m==0) +
// store to Gsw. Round-4 verified. grid = 128 blocks.
// ---------------------------------------------------------------------------
__global__ __launch_bounds__(256, 1) void g_kernel(const u16* __restrict__ Rt,
                                                   const u16* __restrict__ L,
                                                   const float* __restrict__ D,
                                                   u16* __restrict__ Gsw)
{
    __shared__ u16 lds[64 * 72];
    const int m = blockIdx.x;
    const int q = m >> 4, r = m & 15;
    const u16* ap0 = Rt + (size_t)q * BLK;
    const u16* bT0 = L  + (size_t)r * BLK;

    const int tid = threadIdx.x;
    const int w = tid >> 6, l = tid & 63;
    const int lr = l & 15, q8 = (l >> 4) * 8;

    const u16* ap  = ap0 + (size_t)(w * 16 + lr) * NS + q8;
    const u16* bp0 = bT0 + (size_t)lr * NS + q8;

    f32x4 acc[4];
    const f32x4 zero = {0.f, 0.f, 0.f, 0.f};
    #pragma unroll
    for (int nt = 0; nt < 4; ++nt) acc[nt] = zero;

    #pragma unroll 4
    for (int ks = 0; ks < 16; ++ks) {
        const bf16x8 a = *(const bf16x8*)(ap + ks * 32);
        #pragma unroll
        for (int nt = 0; nt < 4; ++nt) {
            const bf16x8 bfr = *(const bf16x8*)(bp0 + (size_t)nt * 16 * NS + ks * 32);
            acc[nt] = __builtin_amdgcn_mfma_f32_16x16x32_bf16(a, bfr, acc[nt], 0, 0, 0);
        }
    }

    // acc[nt][reg]: i (row) = w*16 + (l>>4)*4 + reg, o (col) = nt*16 + lr.
    const int rr = (l >> 4) * 4;
    #pragma unroll
    for (int nt = 0; nt < 4; ++nt)       // lds[o][i] = f2bf(G_m[o][i])
        #pragma unroll
        for (int rk = 0; rk < 4; ++rk)
            lds[(nt * 16 + lr) * 72 + (w * 16 + rr + rk)] = f2bf(acc[nt][rk]);
    __syncthreads();

    const int f = tid >> 6;              // 0..3
    #pragma unroll
    for (int f2 = 0; f2 < 8; f2 += 4) {  // fragments f and f+4
        const int fi = f2 + f;
        const int ks = fi >> 2, nt = fi & 3;
        const int o  = nt * 16 + (l & 15);
        const int i0 = ks * 32 + (l >> 4) * 8;
        u16 v[8];
        #pragma unroll
        for (int j = 0; j < 8; ++j) {
            u16 gv = lds[o * 72 + i0 + j];
            if (m == 0) gv = f2bf(bf2f(gv) + D[o * 64 + i0 + j]);
            v[j] = gv;
        }
        ushort4 p0; p0.x = v[0]; p0.y = v[1]; p0.z = v[2]; p0.w = v[3];
        ushort4 p1; p1.x = v[4]; p1.y = v[5]; p1.z = v[6]; p1.w = v[7];
        u16* dst = Gsw + ((size_t)(m * 8 + fi) * 64 + l) * 8;
        *(ushort4*)(dst + 0) = p0;
        *(ushort4*)(dst + 4) = p1;
    }
}

// ---------------------------------------------------------------------------
// conv_kernel: y[b,t,o] = sum_m sum_i G_m[o][i] xbf[t-m][i]  (+ D via G_0).
// Round-7 changes vs r6 (75.4us, MfmaUtil 38%):
//  1. CTILE 128->256, 4 waves x 64 rows (mt=4): 32 MFMA per 16 LDS reads
//     per wave (was 16 per 12) -- r6 showed the LDS read port, not L1, is
//     the cap (~96 b128 reads/CU/lag ~500cy vs 155cy MFMA).
//     LDS = 55,152 Xs + 32,768 Gs = 88 KB -> 1 block/CU, grid 16x16=256.
//  2. X staged DIRECTLY from fp32 x with in-kernel f2bf (+ zero-fill t<0):
//     prep_x kernel and the xbf buffer are deleted. Same RNE conversion ->
//     identical staged values; same per-element accumulation order ->
//     y bit-identical (absmax must stay exactly 0.09375).
// ---------------------------------------------------------------------------
__global__ __launch_bounds__(256, 1) void conv_kernel(const float* __restrict__ x,
                                                      const u16* __restrict__ gsw,
                                                      float* __restrict__ y)
{
    __shared__ u16 Xs[XROWS * XSTR];   // 383*72*2 = 55,152 B
    __shared__ uint4 Gs[2][1024];      // 32,768 B (2 x {2 lags x 8 frags x 64 lanes})

    const int tid = threadIdx.x;
    const int b  = blockIdx.y;
    const int t0 = blockIdx.x * CTILE;

    // Stage rows r = 0..382 -> time t = t0 + r - 127 (zero-fill t < 0),
    // converting fp32 -> bf16 in-flight. 16 lanes x float4 per row.
    {
        const int g = tid & 15;
        int r = tid >> 4;                    // 0..15
        #pragma unroll
        for (int it = 0; it < 24; ++it, r += 16) {
            if (r < XROWS) {
                const int t = t0 + r - (TLAG - 1);
                ushort4 o;
                if (t < 0) {
                    o.x = 0; o.y = 0; o.z = 0; o.w = 0;
                } else {
                    const float4 v = *(const float4*)(x + ((size_t)b * SEQ + t) * 64 + g * 4);
                    o.x = f2bf(v.x); o.y = f2bf(v.y); o.z = f2bf(v.z); o.w = f2bf(v.w);
                }
                *(ushort4*)&Xs[r * XSTR + g * 4] = o;
            }
        }
    }

    const uint4* gp4 = (const uint4*)gsw;
    uint4 st[4];
    #pragma unroll
    for (int j = 0; j < 4; ++j) st[j] = gp4[tid + j * 256];   // pair 0

    const int w    = tid >> 6;         // 0..3
    const int l    = tid & 63;
    const int lr   = l & 15;
    const int q8   = (l >> 4) * 8;
    const int wrow = w * 64;           // 64 time-rows per wave (4 mt-tiles)

    f32x4 acc[4][4];
    const f32x4 zero = {0.f, 0.f, 0.f, 0.f};
    #pragma unroll
    for (int mt = 0; mt < 4; ++mt)
        #pragma unroll
        for (int nt = 0; nt < 4; ++nt) acc[mt][nt] = zero;

    #pragma unroll
    for (int j = 0; j < 4; ++j) Gs[0][tid + j * 256] = st[j];
    __syncthreads();

    for (int p = 0; p < 64; ++p) {            // pair of lags {2p, 2p+1}
        const int cur = p & 1;
        if (p < 63) {
            #pragma unroll
            for (int j = 0; j < 4; ++j) st[j] = gp4[(p + 1) * 1024 + tid + j * 256];
        }
        #pragma unroll
        for (int sub = 0; sub < 2; ++sub) {
            const int m = 2 * p + sub;
            bf16x8 bc[8];
            #pragma unroll
            for (int f = 0; f < 8; ++f)
                bc[f] = __builtin_bit_cast(bf16x8, Gs[cur][sub * 512 + f * 64 + l]);

            const int rbase = wrow + lr + (TLAG - 1) - m;
            bf16x8 a[4][2];
            #pragma unroll
            for (int mt = 0; mt < 4; ++mt)
                #pragma unroll
                for (int ks = 0; ks < 2; ++ks)
                    a[mt][ks] = *(const bf16x8*)&Xs[(rbase + mt * 16) * XSTR + ks * 32 + q8];

            #pragma unroll
            for (int ks = 0; ks < 2; ++ks)
                #pragma unroll
                for (int mt = 0; mt < 4; ++mt)
                    #pragma unroll
                    for (int nt = 0; nt < 4; ++nt)
                        acc[mt][nt] = __builtin_amdgcn_mfma_f32_16x16x32_bf16(
                            a[mt][ks], bc[ks * 4 + nt], acc[mt][nt], 0, 0, 0);
        }
        if (p < 63) {
            #pragma unroll
            for (int j = 0; j < 4; ++j) Gs[cur ^ 1][tid + j * 256] = st[j];
        }
        __syncthreads();
    }

    // Epilogue: C/D layout col = lane&15 (out-feature), row = (lane>>4)*4+reg (time).
    const int rr = (l >> 4) * 4;
    #pragma unroll
    for (int mt = 0; mt < 4; ++mt) {
        #pragma unroll
        for (int nt = 0; nt < 4; ++nt) {
            const int t = t0 + wrow + mt * 16 + rr;
            const int o = nt * 16 + lr;
            float* yp = y + ((size_t)b * SEQ + t) * 64 + o;
            #pragma unroll
            for (int r = 0; r < 4; ++r) yp[(size_t)r * 64] = acc[mt][nt][r];
        }
    }
}

// ---------------------------------------------------------------------------
// Workspace layout (bytes, 16-aligned) — offsets kept from round 4 (xbf slot
// now unused; no growth in required ws_size):
//   8,650,752   Arm       524,288   (A row-major)
//   9,175,040   At        524,288   (A^T)
//   9,699,328   A2rm      524,288
//  10,223,616   A2t       524,288
//  10,747,904   A4rm      524,288
//  11,272,192   A4t       524,288
//  11,796,480   A8rm      524,288
//  12,320,768   A8t       524,288
//  12,845,056   A16rm     524,288
//  13,369,344   A16t      524,288
//  13,893,632   A32rm     524,288
//  14,417,920   A32t      524,288
//  14,942,208   A64rm     524,288
//  15,532,032   L       1,048,576   (L_r = C A^r, r<16, RM row-blocks)
//  16,580,608   Rt        524,288   (R_q^T = (A^{16q} B)^T, q<8)
//  17,104,896   Gsw     1,048,576   (B-fragment-swizzled conv kernels)
//  total: 18,153,472
// ---------------------------------------------------------------------------
extern "C" void kernel_launch(void* const* d_in, const int* in_sizes, int n_in,
                              void* d_out, int out_size, void* d_ws, size_t ws_size,
                              hipStream_t stream)
{
    const float* x = (const float*)d_in[0];
    const float* A = (const float*)d_in[1];
    const float* B = (const float*)d_in[2];
    const float* C = (const float*)d_in[3];
    const float* D = (const float*)d_in[4];
    float* y = (float*)d_out;

    char* w = (char*)d_ws;
    u16* Arm   = (u16*)(w + 8650752);
    u16* At    = (u16*)(w + 9175040);
    u16* A2rm  = (u16*)(w + 9699328);
    u16* A2t   = (u16*)(w + 10223616);
    u16* A4rm  = (u16*)(w + 10747904);
    u16* A4t   = (u16*)(w + 11272192);
    u16* A8rm  = (u16*)(w + 11796480);
    u16* A8t   = (u16*)(w + 12320768);
    u16* A16rm = (u16*)(w + 12845056);
    u16* A16t  = (u16*)(w + 13369344);
    u16* A32rm = (u16*)(w + 13893632);
    u16* A32t  = (u16*)(w + 14417920);
    u16* A64rm = (u16*)(w + 14942208);
    u16* L     = (u16*)(w + 15532032);
    u16* Rt    = (u16*)(w + 16580608);
    u16* Gsw   = (u16*)(w + 17104896);

    prep_mat<<<1280, 256, 0, stream>>>(A, B, C, Arm, At, Rt, L);

    // Stage 1: L[1] = L[0]*A           ; A2  = A*A        (8 + 64 blocks)
    stage_kernel<<<72, 256, 0, stream>>>(L, At, L + 1 * BLK,
                                         Arm, At, A2rm, A2t, 8);
    // Stage 2: L[2+j] = L[j]*A2, j<2   ; A4  = A2*A2      (16 + 64)
    stage_kernel<<<80, 256, 0, stream>>>(L, A2t, L + 2 * BLK,
                                         A2rm, A2t, A4rm, A4t, 16);
    // Stage 3: L[4+j] = L[j]*A4, j<4   ; A8  = A4*A4      (32 + 64)
    stage_kernel<<<96, 256, 0, stream>>>(L, A4t, L + 4 * BLK,
                                         A4rm, A4t, A8rm, A8t, 32);
    // Stage 4: L[8+j] = L[j]*A8, j<8   ; A16 = A8*A8      (64 + 64)
    stage_kernel<<<128, 256, 0, stream>>>(L, A8t, L + 8 * BLK,
                                          A8rm, A8t, A16rm, A16t, 64);
    // Stage 5: R[1]^T = R[0]^T*A16^T   ; A32 = A16*A16    (8 + 64)
    stage_kernel<<<72, 256, 0, stream>>>(Rt, A16rm, Rt + 1 * BLK,
                                         A16rm, A16t, A32rm, A32t, 8);
    // Stage 6: R[2+j]^T = R[j]^T*A32^T ; A64 = A32*A32 (RM only) (16 + 64)
    stage_kernel<<<80, 256, 0, stream>>>(Rt, A32rm, Rt + 2 * BLK,
                                         A32rm, A32t, A64rm, nullptr, 16);
    // Stage 7: R[4+j]^T = R[j]^T*A64^T, j<4                (32)
    stage_kernel<<<32, 256, 0, stream>>>(Rt, A64rm, Rt + 4 * BLK,
                                         nullptr, nullptr, nullptr, nullptr, 32);
    // Stage 8: G_m = L_r R_q, swizzled + D fold            (128)
    g_kernel<<<128, 256, 0, stream>>>(Rt, L, D, Gsw);

    conv_kernel<<<dim3(SEQ / CTILE, BATCH), 256, 0, stream>>>(x, Gsw, y);
}